// Round 1
// 639.533 us; speedup vs baseline: 1.1019x; 1.1019x over previous
//
#include <hip/hip_runtime.h>
#include <hip/hip_bf16.h>
#include <math.h>

// Problem constants
#define BB 8
#define SS 1024
#define DD 2048
#define HH 16
#define DHD 128

typedef float  v4f  __attribute__((ext_vector_type(4)));
typedef short  v4s  __attribute__((ext_vector_type(4)));
typedef short  v8s  __attribute__((ext_vector_type(8)));
typedef __bf16 v8bf __attribute__((ext_vector_type(8)));

#define GLOBAL_AS __attribute__((address_space(1)))
#define LDS_AS    __attribute__((address_space(3)))

__device__ __forceinline__ unsigned short f2b(float f) {
    union { float f; unsigned int u; } x; x.f = f;
    unsigned int r = x.u + 0x7fffu + ((x.u >> 16) & 1u);  // RNE
    return (unsigned short)(r >> 16);
}

__device__ __forceinline__ v8bf ldsv8(const unsigned short* p) {
    return __builtin_bit_cast(v8bf, *(const v8s*)p);
}

// ---------------------------------------------------------------------------
// fp32 -> bf16 elementwise convert (memory-bound)
// ---------------------------------------------------------------------------
__global__ __launch_bounds__(256) void cvt_f32_bf16(const float* __restrict__ src,
                                                    unsigned short* __restrict__ dst,
                                                    int n4) {
    int i = blockIdx.x * blockDim.x + threadIdx.x;
    int stride = gridDim.x * blockDim.x;
    for (; i < n4; i += stride) {
        v4f f = ((const v4f*)src)[i];
        v4s o;
        o[0] = (short)f2b(f[0]); o[1] = (short)f2b(f[1]);
        o[2] = (short)f2b(f[2]); o[3] = (short)f2b(f[3]);
        ((v4s*)dst)[i] = o;
    }
}

// ---------------------------------------------------------------------------
// W (K x N fp32, row-major) -> WT (N x K bf16, row-major). LDS-tiled transpose.
// ---------------------------------------------------------------------------
__global__ __launch_bounds__(256) void wtrans_kernel(const float* __restrict__ W,
                                                     unsigned short* __restrict__ WT) {
    __shared__ float t[64][65];
    int nb = blockIdx.x * 64;
    int kb = blockIdx.y * 64;
    int tr = threadIdx.x >> 4;         // 0..15
    int tc = (threadIdx.x & 15) * 4;   // 0..60
#pragma unroll
    for (int i = 0; i < 4; i++) {
        int k = kb + tr + i * 16;
        v4f v = *(const v4f*)(W + (size_t)k * DD + nb + tc);
        t[tr + i * 16][tc + 0] = v[0];
        t[tr + i * 16][tc + 1] = v[1];
        t[tr + i * 16][tc + 2] = v[2];
        t[tr + i * 16][tc + 3] = v[3];
    }
    __syncthreads();
#pragma unroll
    for (int i = 0; i < 4; i++) {
        int n = nb + tr + i * 16;
        v4s o;
#pragma unroll
        for (int j = 0; j < 4; j++) o[j] = (short)f2b(t[tc + j][tr + i * 16]);
        *(v4s*)(WT + (size_t)n * DD + kb + tc) = o;
    }
}

// ---------------------------------------------------------------------------
// 256x256-tile, BK=64, 8-wave, double-buffered bf16 GEMM with
// counted-vmcnt phase-interleaved schedule (T2+T3+T4+T5).
//   C[m][n] = sum_k A[m][k] * BT[n][k]
//
// Geometry: 512 thr = 8 waves (2M x 4N), per-wave C = 128x64 (8x4 frags of
// 16x16). LDS 128 KiB: sA/sB each 2 x [256][64] bf16. Per K-tile: 4 phases,
// each = {ds_read frags ; 2x global_load_lds prefetch ; bar ; prio1 ;
// 16 MFMA ; prio0 ; lgkm0 ; bar}.
//
// Staging groups match per-phase consumption so an issued prefetch never
// targets a region with reads still pending (>=1 barrier after last read,
// reads lgkm-drained before each barrier):
//   A group g = rows [g*64,+64) u [128+g*64,+64)   (phase mh reads group mh)
//   B group g = rows {r : (r>>5)&1 == g}           (phase nh reads group nh)
// Schedule: p0 stages Ag1(t+1)->nbuf, p1 Bg1(t+1)->nbuf,
//           p2 Ag0(t+2)->buf, p3 Bg0(t+2)->buf.
// Boundary: one s_waitcnt vmcnt(4) per tile (2 staging groups stay in
// flight across the barrier; never drained to 0 until the tail).
//
// Swizzle: LDS rows are 128B (power-of-2) so frag reads would hit the same
// banks for all 16 rows. 16B chunks are XOR-permuted on the GLOBAL side of
// global_load_lds (LDS dest must stay linear): phys_chunk = logical ^ (row&7).
// Readers apply the same XOR -> even bank spread.
// ---------------------------------------------------------------------------
__global__ __launch_bounds__(512, 2) void gemm256(const unsigned short* __restrict__ A,
                                                  const unsigned short* __restrict__ BT,
                                                  unsigned short* __restrict__ C,
                                                  float scale, int vmode,
                                                  int M, int N, int K) {
    __shared__ __align__(16) unsigned short sA[2 * 16384];   // 2 x 256 x 64
    __shared__ __align__(16) unsigned short sB[2 * 16384];

    const int tid  = threadIdx.x;
    const int lane = tid & 63;
    const int w    = tid >> 6;        // 0..7
    const int qcol = lane & 15;
    const int quad = lane >> 4;
    const int l3   = lane >> 3;       // 0..7 row-within-8 for staging
    const int l7   = lane & 7;

    const int ntn = N >> 8;
    const int bn  = (blockIdx.x % ntn) * 256;   // bid%8 -> XCD-pinned B panel
    const int bm  = (blockIdx.x / ntn) * 256;

    const int wm = (w >> 2) * 128;    // 0 / 128
    const int wn = (w & 3) * 64;      // 0..192

    // --- staging addresses: inst = w*2+jj (0..15), 8 rows x 16B per inst ---
    const int gchunk = (l7 ^ l3) * 8;           // swizzled global chunk (elts)
    const unsigned short* pA[2];
    const unsigned short* pB[2];
    int ldsArow[2], ldsBrow[2];
#pragma unroll
    for (int jj = 0; jj < 2; jj++) {
        int inst = w * 2 + jj;
        int ra = (inst >> 3) * 128 + (inst & 7) * 8;   // A row base (g=0)
        int rb = (inst >> 2) * 64 + (inst & 3) * 8;    // B row base (g=0)
        pA[jj] = A  + (size_t)(bm + ra + l3) * K + gchunk;
        pB[jj] = BT + (size_t)(bn + rb + l3) * K + gchunk;
        ldsArow[jj] = ra * 64;
        ldsBrow[jj] = rb * 64;
    }

    // --- fragment-read constants ---
    const int c0   = ((quad ^ l7) & 7) * 8;   // ks=0 phys chunk (ushort off)
    const int c1   = c0 ^ 32;                 // ks=1 (logical+4 -> ^4 chunks)
    const int aRow = (wm + qcol) * 64;
    const int bRow = (wn + qcol) * 64;

    v4f acc[8][4];
#pragma unroll
    for (int i = 0; i < 8; i++)
#pragma unroll
        for (int j = 0; j < 4; j++) acc[i][j] = (v4f){0.f, 0.f, 0.f, 0.f};

    v8bf af[4][2];    // A frags of current mh (4 m-frags x 2 ksteps)
    v8bf bf2[2][2];   // B frags of current nh (2 n-frags x 2 ksteps)

    auto STAGE_A = [&](int b_, int g_, int t_) {
#pragma unroll
        for (int jj = 0; jj < 2; jj++)
            __builtin_amdgcn_global_load_lds(
                (const GLOBAL_AS void*)(pA[jj] + (size_t)g_ * 64 * K + (size_t)t_ * 64),
                (LDS_AS void*)(&sA[b_ * 16384 + ldsArow[jj] + g_ * 4096]), 16, 0, 0);
    };
    auto STAGE_B = [&](int b_, int g_, int t_) {
#pragma unroll
        for (int jj = 0; jj < 2; jj++)
            __builtin_amdgcn_global_load_lds(
                (const GLOBAL_AS void*)(pB[jj] + (size_t)g_ * 32 * K + (size_t)t_ * 64),
                (LDS_AS void*)(&sB[b_ * 16384 + ldsBrow[jj] + g_ * 2048]), 16, 0, 0);
    };

    const int nt = K >> 6;   // K-tiles (BK=64); nt >= 2

    // --- prologue: tile0 all 4 groups + tile1 g0 groups (12 loads) ---
    STAGE_A(0, 0, 0); STAGE_B(0, 0, 0);
    STAGE_A(0, 1, 0); STAGE_B(0, 1, 0);
    STAGE_A(1, 0, 1); STAGE_B(1, 0, 1);
    asm volatile("s_waitcnt vmcnt(4)" ::: "memory");
    __builtin_amdgcn_s_barrier();

    for (int t = 0; t < nt; ++t) {
        const int buf = t & 1, nbuf = buf ^ 1;
        const unsigned short* sAb = &sA[buf * 16384];
        const unsigned short* sBb = &sB[buf * 16384];
        const bool st1 = (t + 1 < nt);
        const bool st2 = (t + 2 < nt);

        auto LDA = [&](int mh) {
            const unsigned short* base = sAb + aRow + mh * 4096;
#pragma unroll
            for (int i = 0; i < 4; i++) {
                af[i][0] = ldsv8(base + i * 1024 + c0);
                af[i][1] = ldsv8(base + i * 1024 + c1);
            }
        };
        auto LDB = [&](int nh) {
            const unsigned short* base = sBb + bRow + nh * 2048;
#pragma unroll
            for (int j = 0; j < 2; j++) {
                bf2[j][0] = ldsv8(base + j * 1024 + c0);
                bf2[j][1] = ldsv8(base + j * 1024 + c1);
            }
        };
        auto MMA = [&](int mh, int nh) {
            __builtin_amdgcn_s_setprio(1);
#pragma unroll
            for (int i = 0; i < 4; i++)
#pragma unroll
                for (int j = 0; j < 2; j++) {
                    acc[mh * 4 + i][nh * 2 + j] = __builtin_amdgcn_mfma_f32_16x16x32_bf16(
                        af[i][0], bf2[j][0], acc[mh * 4 + i][nh * 2 + j], 0, 0, 0);
                    acc[mh * 4 + i][nh * 2 + j] = __builtin_amdgcn_mfma_f32_16x16x32_bf16(
                        af[i][1], bf2[j][1], acc[mh * 4 + i][nh * 2 + j], 0, 0, 0);
                }
            __builtin_amdgcn_s_setprio(0);
        };

        // ---- phase 0: (mh0,nh0); stage Ag1(t+1) -> nbuf
        LDA(0);
        LDB(0);
        if (st1) STAGE_A(nbuf, 1, t + 1);
        __builtin_amdgcn_s_barrier();
        MMA(0, 0);
        asm volatile("s_waitcnt lgkmcnt(0)" ::: "memory");
        __builtin_amdgcn_s_barrier();

        // ---- phase 1: (mh0,nh1); stage Bg1(t+1) -> nbuf
        LDB(1);
        if (st1) STAGE_B(nbuf, 1, t + 1);
        __builtin_amdgcn_s_barrier();
        MMA(0, 1);
        asm volatile("s_waitcnt lgkmcnt(0)" ::: "memory");
        __builtin_amdgcn_s_barrier();

        // ---- phase 2: (mh1,nh0); stage Ag0(t+2) -> buf (A g0 freed @p1)
        LDA(1);
        LDB(0);
        if (st2) STAGE_A(buf, 0, t + 2);
        __builtin_amdgcn_s_barrier();
        MMA(1, 0);
        asm volatile("s_waitcnt lgkmcnt(0)" ::: "memory");
        __builtin_amdgcn_s_barrier();

        // ---- phase 3: (mh1,nh1); stage Bg0(t+2) -> buf (B g0 freed @p2)
        LDB(1);
        if (st2) STAGE_B(buf, 0, t + 2);
        __builtin_amdgcn_s_barrier();
        MMA(1, 1);
        if (t < nt - 2)
            asm volatile("s_waitcnt lgkmcnt(0) vmcnt(4)" ::: "memory");
        else
            asm volatile("s_waitcnt lgkmcnt(0) vmcnt(0)" ::: "memory");
        __builtin_amdgcn_s_barrier();
    }

    // ---- epilogue ----
    if (vmode == 0) {
#pragma unroll
        for (int mi = 0; mi < 8; mi++)
#pragma unroll
            for (int nj = 0; nj < 4; nj++)
#pragma unroll
                for (int r = 0; r < 4; r++) {
                    int row = bm + wm + mi * 16 + quad * 4 + r;
                    int col = bn + wn + nj * 16 + qcol;
                    C[(size_t)row * N + col] = f2b(acc[mi][nj][r] * scale);
                }
    } else {
#pragma unroll
        for (int mi = 0; mi < 8; mi++)
#pragma unroll
            for (int nj = 0; nj < 4; nj++)
#pragma unroll
                for (int r = 0; r < 4; r++) {
                    int row = bm + wm + mi * 16 + quad * 4 + r;
                    int col = bn + wn + nj * 16 + qcol;
                    size_t idx = ((size_t)(row >> 10) * 2048 + col) * 1024 + (row & 1023);
                    C[idx] = f2b(acc[mi][nj][r] * scale);
                }
    }
}

// ---------------------------------------------------------------------------
// Flash attention v3: LDS-staged K/V shared by all 4 waves, GEMM-style
// 2-barrier K-loop with global_load_lds width=16, 64-key tiles.
//
// Swizzle: LDS rows have power-of-2 byte strides (K: 256B, V: 128B), so
// naive fragment reads would be 16-way bank-conflicted. We XOR-permute the
// 16B chunks on the GLOBAL side of the staging load (per-lane global
// addresses are unconstrained; LDS dest must stay uniform + lane*16):
//   sK[key][chunk c] = K[key][c ^ (key&15)]   (16 chunks of 16B per row)
//   sV[d][chunk c]   = V^T[d][c ^ (d&7)]      (8 chunks of 16B per row)
// Readers XOR the same way -> 2-way-max aliasing (free per m136).
// ---------------------------------------------------------------------------
__global__ __launch_bounds__(256, 4) void attn_kernel(const unsigned short* __restrict__ qh,
                                                      const unsigned short* __restrict__ kh,
                                                      const unsigned short* __restrict__ vt,
                                                      float* __restrict__ out) {
    __shared__ __align__(16) unsigned short sK[64 * 128];   // [key][d] 64 rows x 256B
    __shared__ __align__(16) unsigned short sV[128 * 64];   // [d][key] 128 rows x 128B

    int lane = threadIdx.x & 63, w = threadIdx.x >> 6;
    int b = blockIdx.z, h = blockIdx.y;
    int q0 = blockIdx.x * 64 + w * 16;
    int qcol = lane & 15, quad = lane >> 4;

    // Q fragments (B-operand of 16x16x32): n = q = lane&15, k = d
    const unsigned short* qp = qh + (size_t)(b * SS + q0 + qcol) * DD + h * DHD;
    v8bf bq[4];
#pragma unroll
    for (int kk = 0; kk < 4; kk++)
        bq[kk] = __builtin_bit_cast(v8bf, *(const v8s*)(qp + kk * 32 + quad * 8));

    // --- staging addresses (element offsets within current tile) ---
    int ko[4];
#pragma unroll
    for (int j = 0; j < 4; j++) {
        int key = w * 16 + j * 4 + (lane >> 4);
        ko[j] = key * DD + (((lane & 15) ^ (key & 15)) * 8);
    }
    int vo0 = (w * 32 + (lane >> 3)) * SS + (((lane & 7) ^ (lane >> 3)) * 8);

    const unsigned short* kcur = kh + (size_t)b * SS * DD + h * DHD;
    const unsigned short* vcur = vt + (size_t)(b * HH + h) * DHD * SS;
    unsigned short* kl0 = &sK[(w * 16) * 128];
    unsigned short* vl0 = &sV[(w * 32) * 64];

    float m_i = -1e30f, l_i = 0.f;
    v4f acc[8];
#pragma unroll
    for (int c = 0; c < 8; c++) acc[c] = (v4f){0.f, 0.f, 0.f, 0.f};

    for (int kb = 0; kb < SS; kb += 64) {
        __syncthreads();   // previous tile's LDS reads complete
#pragma unroll
        for (int j = 0; j < 4; j++)
            __builtin_amdgcn_global_load_lds((const GLOBAL_AS void*)(kcur + ko[j]),
                                             (LDS_AS void*)(kl0 + j * 4 * 128), 16, 0, 0);
#pragma unroll
        for (int j = 0; j < 4; j++)
            __builtin_amdgcn_global_load_lds((const GLOBAL_AS void*)(vcur + vo0 + j * 8 * SS),
                                             (LDS_AS void*)(vl0 + j * 8 * 64), 16, 0, 0);
        kcur += (size_t)64 * DD;
        vcur += 64;
        __syncthreads();   // staging drained

        // S^T = K.Q^T : 16 MFMA 16x16x32, fragments from swizzled sK
        v4f s[4];
#pragma unroll
        for (int kf = 0; kf < 4; kf++) {
            s[kf] = (v4f){0.f, 0.f, 0.f, 0.f};
#pragma unroll
            for (int kk = 0; kk < 4; kk++) {
                v8bf ak = __builtin_bit_cast(v8bf,
                    *(const v8s*)&sK[(kf * 16 + qcol) * 128 + (((kk * 4 + quad) ^ qcol) * 8)]);
                s[kf] = __builtin_amdgcn_mfma_f32_16x16x32_bf16(ak, bq[kk], s[kf], 0, 0, 0);
            }
        }

        // online softmax over 64 keys (base-2; log2(e) folded into qh scale)
        float mx = -1e30f;
#pragma unroll
        for (int kf = 0; kf < 4; kf++)
#pragma unroll
            for (int r = 0; r < 4; r++) mx = fmaxf(mx, s[kf][r]);
        mx = fmaxf(mx, __shfl_xor(mx, 16));
        mx = fmaxf(mx, __shfl_xor(mx, 32));
        float m_new = fmaxf(m_i, mx);
        float rs = 0.f;
        v4s p[4];
#pragma unroll
        for (int kf = 0; kf < 4; kf++)
#pragma unroll
            for (int r = 0; r < 4; r++) {
                float pf = exp2f(s[kf][r] - m_new);
                rs += pf;
                p[kf][r] = (short)f2b(pf);
            }
        rs += __shfl_xor(rs, 16);
        rs += __shfl_xor(rs, 32);
        float alpha = exp2f(m_i - m_new);
        l_i = l_i * alpha + rs;
        m_i = m_new;
#pragma unroll
        for (int c = 0; c < 8; c++) {
            acc[c][0] *= alpha; acc[c][1] *= alpha;
            acc[c][2] *= alpha; acc[c][3] *= alpha;
        }

        // PV: 32 MFMA 16x16x16, V fragments from swizzled sV
#pragma unroll
        for (int c = 0; c < 8; c++) {
            int row = (c * 16 + qcol) * 64;
#pragma unroll
            for (int kf = 0; kf < 4; kf++) {
                v4s av = *(const v4s*)&sV[row + (((kf * 2 + (quad >> 1)) ^ (qcol & 7)) * 8)
                                              + (quad & 1) * 4];
                acc[c] = __builtin_amdgcn_mfma_f32_16x16x16bf16_1k(av, p[kf], acc[c], 0, 0, 0);
            }
        }
    }

    float rl = 1.0f / l_i;
    float* op = out + (size_t)(b * SS + q0 + qcol) * DD + h * DHD;
#pragma unroll
    for (int c = 0; c < 8; c++)
#pragma unroll
        for (int r = 0; r < 4; r++)
            op[c * 16 + quad * 4 + r] = acc[c][r] * rl;
}

// ---------------------------------------------------------------------------
// Launch. ws layout (needs 136 MB):
//   abuf @ 0 MB (32) | wbuf @ 32 (8) | qh @ 40 (32) | kh @ 72 (32) | vt @ 104 (32)
// ---------------------------------------------------------------------------
extern "C" void kernel_launch(void* const* d_in, const int* in_sizes, int n_in,
                              void* d_out, int out_size, void* d_ws, size_t ws_size,
                              hipStream_t stream) {
    const float* ins[3]  = {(const float*)d_in[0], (const float*)d_in[1], (const float*)d_in[2]};
    const float* wins[3] = {(const float*)d_in[3], (const float*)d_in[4], (const float*)d_in[5]};
    char* ws = (char*)d_ws;
    unsigned short* abuf = (unsigned short*)(ws);
    unsigned short* wbuf = (unsigned short*)(ws + (size_t)32 * 1024 * 1024);
    unsigned short* qhb  = (unsigned short*)(ws + (size_t)40 * 1024 * 1024);
    unsigned short* khb  = (unsigned short*)(ws + (size_t)72 * 1024 * 1024);
    unsigned short* vtb  = (unsigned short*)(ws + (size_t)104 * 1024 * 1024);
    float* out = (float*)d_out;

    unsigned short* outs[3] = {qhb, khb, vtb};
    const float qscale = 0.12753139626246937f;  // log2(e)/sqrt(128)
    float scales[3] = {qscale, 1.f, 1.f};
    int   vmodes[3] = {0, 0, 1};

    const int M = BB * SS, N = DD, K = DD;
    const int grid = (M / 256) * (N / 256);   // 32*8 = 256 WGs = 1/CU

    for (int i = 0; i < 3; i++) {
        cvt_f32_bf16<<<dim3(4096), dim3(256), 0, stream>>>(ins[i], abuf, (BB * SS * DD) / 4);
        wtrans_kernel<<<dim3(32, 32), dim3(256), 0, stream>>>(wins[i], wbuf);
        gemm256<<<dim3(grid), dim3(512), 0, stream>>>(abuf, wbuf, outs[i],
                                                      scales[i], vmodes[i], M, N, K);
    }
    attn_kernel<<<dim3(SS / 64, HH, BB), dim3(256), 0, stream>>>(qhb, khb, vtb, out);
}

// Round 2
// 637.740 us; speedup vs baseline: 1.1050x; 1.0028x over previous
//
#include <hip/hip_runtime.h>
#include <hip/hip_bf16.h>
#include <math.h>

// Problem constants
#define BB 8
#define SS 1024
#define DD 2048
#define HH 16
#define DHD 128

typedef float  v4f  __attribute__((ext_vector_type(4)));
typedef short  v4s  __attribute__((ext_vector_type(4)));
typedef short  v8s  __attribute__((ext_vector_type(8)));
typedef __bf16 v8bf __attribute__((ext_vector_type(8)));

#define GLOBAL_AS __attribute__((address_space(1)))
#define LDS_AS    __attribute__((address_space(3)))

__device__ __forceinline__ unsigned short f2b(float f) {
    union { float f; unsigned int u; } x; x.f = f;
    unsigned int r = x.u + 0x7fffu + ((x.u >> 16) & 1u);  // RNE
    return (unsigned short)(r >> 16);
}

__device__ __forceinline__ v8bf ldsv8(const unsigned short* p) {
    return __builtin_bit_cast(v8bf, *(const v8s*)p);
}

// ---------------------------------------------------------------------------
// fp32 -> bf16 elementwise convert (memory-bound)
// ---------------------------------------------------------------------------
__global__ __launch_bounds__(256) void cvt_f32_bf16(const float* __restrict__ src,
                                                    unsigned short* __restrict__ dst,
                                                    int n4) {
    int i = blockIdx.x * blockDim.x + threadIdx.x;
    int stride = gridDim.x * blockDim.x;
    for (; i < n4; i += stride) {
        v4f f = ((const v4f*)src)[i];
        v4s o;
        o[0] = (short)f2b(f[0]); o[1] = (short)f2b(f[1]);
        o[2] = (short)f2b(f[2]); o[3] = (short)f2b(f[3]);
        ((v4s*)dst)[i] = o;
    }
}

// ---------------------------------------------------------------------------
// W (K x N fp32, row-major) -> WT (N x K bf16, row-major). LDS-tiled transpose.
// ---------------------------------------------------------------------------
__global__ __launch_bounds__(256) void wtrans_kernel(const float* __restrict__ W,
                                                     unsigned short* __restrict__ WT) {
    __shared__ float t[64][65];
    int nb = blockIdx.x * 64;
    int kb = blockIdx.y * 64;
    int tr = threadIdx.x >> 4;         // 0..15
    int tc = (threadIdx.x & 15) * 4;   // 0..60
#pragma unroll
    for (int i = 0; i < 4; i++) {
        int k = kb + tr + i * 16;
        v4f v = *(const v4f*)(W + (size_t)k * DD + nb + tc);
        t[tr + i * 16][tc + 0] = v[0];
        t[tr + i * 16][tc + 1] = v[1];
        t[tr + i * 16][tc + 2] = v[2];
        t[tr + i * 16][tc + 3] = v[3];
    }
    __syncthreads();
#pragma unroll
    for (int i = 0; i < 4; i++) {
        int n = nb + tr + i * 16;
        v4s o;
#pragma unroll
        for (int j = 0; j < 4; j++) o[j] = (short)f2b(t[tc + j][tr + i * 16]);
        *(v4s*)(WT + (size_t)n * DD + kb + tc) = o;
    }
}

// ---------------------------------------------------------------------------
// 256x256-tile, BK=64, 8-wave, double-buffered bf16 GEMM with
// counted-vmcnt phase-interleaved schedule (T2+T3+T4+T5).
//   C[m][n] = sum_k A[m][k] * BT[n][k]
//
// Same schedule as round 1 (verified correct) but codegen-safe: no lambdas,
// no asm "memory" clobbers -> acc[8][4] stays in VGPRs (round 1 spilled it
// to scratch: VGPR_Count=108, 7x slowdown).
//
// Geometry: 512 thr = 8 waves (2M x 4N), per-wave C = 128x64 (8x4 frags of
// 16x16). LDS 128 KiB: sA/sB each 2 x [256][64] bf16.
//
// Staging groups (per-phase consumption; >=1 barrier between last read of a
// region and the STAGE that overwrites it):
//   A group g = rows [g*64,+64) u [128+g*64,+64)   (phase mh reads group mh)
//   B group g = rows {r : (r>>5)&1 == g}           (phase nh reads group nh)
// Schedule: p0 stages Ag1(t+1)->nbuf, p1 Bg1(t+1)->nbuf,
//           p2 Ag0(t+2)->buf, p3 Bg0(t+2)->buf.
// One s_waitcnt vmcnt(4) per tile (2 staging groups / 4 loads per wave stay
// in flight across the tile boundary; drained to 0 only in the last 2 tiles).
//
// Swizzle: LDS rows are 128B (power-of-2): 16B chunks XOR-permuted on the
// GLOBAL side of global_load_lds (LDS dest stays linear, HW requirement):
// phys_chunk = logical ^ (row&7); readers apply the same XOR.
// ---------------------------------------------------------------------------

#define STAGE_A(bb, gg, tt) do {                                              \
    __builtin_amdgcn_global_load_lds(                                         \
        (const GLOBAL_AS void*)(pA0 + (size_t)(gg) * 64 * K + (size_t)(tt) * 64), \
        (LDS_AS void*)(&sA[(bb) * 16384 + ldsA0 + (gg) * 4096]), 16, 0, 0);   \
    __builtin_amdgcn_global_load_lds(                                         \
        (const GLOBAL_AS void*)(pA1 + (size_t)(gg) * 64 * K + (size_t)(tt) * 64), \
        (LDS_AS void*)(&sA[(bb) * 16384 + ldsA1 + (gg) * 4096]), 16, 0, 0);   \
} while (0)

#define STAGE_B(bb, gg, tt) do {                                              \
    __builtin_amdgcn_global_load_lds(                                         \
        (const GLOBAL_AS void*)(pB0 + (size_t)(gg) * 32 * K + (size_t)(tt) * 64), \
        (LDS_AS void*)(&sB[(bb) * 16384 + ldsB0 + (gg) * 2048]), 16, 0, 0);   \
    __builtin_amdgcn_global_load_lds(                                         \
        (const GLOBAL_AS void*)(pB1 + (size_t)(gg) * 32 * K + (size_t)(tt) * 64), \
        (LDS_AS void*)(&sB[(bb) * 16384 + ldsB1 + (gg) * 2048]), 16, 0, 0);   \
} while (0)

// One phase: optional A-frag ds_reads, B-frag ds_reads, prefetch STAGE,
// barrier, lgkm drain, prio-raised 16x MFMA, tail wait, barrier.
// mh/nh/dolda are literal constants.
#define PHASE(mh, nh, dolda, STAGE_STMT, TAIL_STMT) do {                      \
    if (dolda) {                                                              \
        _Pragma("unroll")                                                     \
        for (int i = 0; i < 4; i++) {                                         \
            af[i][0] = ldsv8(sAb + aRow + (mh) * 4096 + i * 1024 + c0);       \
            af[i][1] = ldsv8(sAb + aRow + (mh) * 4096 + i * 1024 + c1);       \
        }                                                                     \
    }                                                                         \
    _Pragma("unroll")                                                         \
    for (int j = 0; j < 2; j++) {                                             \
        bf2[j][0] = ldsv8(sBb + bRow + (nh) * 2048 + j * 1024 + c0);          \
        bf2[j][1] = ldsv8(sBb + bRow + (nh) * 2048 + j * 1024 + c1);          \
    }                                                                         \
    STAGE_STMT;                                                               \
    __builtin_amdgcn_s_barrier();                                             \
    asm volatile("s_waitcnt lgkmcnt(0)");                                     \
    __builtin_amdgcn_sched_barrier(0);                                        \
    __builtin_amdgcn_s_setprio(1);                                            \
    _Pragma("unroll")                                                         \
    for (int i = 0; i < 4; i++) {                                             \
        _Pragma("unroll")                                                     \
        for (int j = 0; j < 2; j++) {                                         \
            acc[(mh) * 4 + i][(nh) * 2 + j] =                                 \
                __builtin_amdgcn_mfma_f32_16x16x32_bf16(                      \
                    af[i][0], bf2[j][0], acc[(mh) * 4 + i][(nh) * 2 + j], 0, 0, 0); \
            acc[(mh) * 4 + i][(nh) * 2 + j] =                                 \
                __builtin_amdgcn_mfma_f32_16x16x32_bf16(                      \
                    af[i][1], bf2[j][1], acc[(mh) * 4 + i][(nh) * 2 + j], 0, 0, 0); \
        }                                                                     \
    }                                                                         \
    __builtin_amdgcn_s_setprio(0);                                            \
    TAIL_STMT;                                                                \
    __builtin_amdgcn_s_barrier();                                             \
} while (0)

__global__ __launch_bounds__(512, 2) void gemm256(const unsigned short* __restrict__ A,
                                                  const unsigned short* __restrict__ BT,
                                                  unsigned short* __restrict__ C,
                                                  float scale, int vmode,
                                                  int M, int N, int K) {
    __shared__ __align__(16) unsigned short sA[2 * 16384];   // 2 x 256 x 64
    __shared__ __align__(16) unsigned short sB[2 * 16384];

    const int tid  = threadIdx.x;
    const int lane = tid & 63;
    const int w    = tid >> 6;        // 0..7
    const int qcol = lane & 15;
    const int quad = lane >> 4;
    const int l3   = lane >> 3;       // 0..7 row-within-8 for staging
    const int l7   = lane & 7;

    const int ntn = N >> 8;
    const int bn  = (blockIdx.x % ntn) * 256;   // bid%8 -> XCD-pinned B panel
    const int bm  = (blockIdx.x / ntn) * 256;

    const int wm = (w >> 2) * 128;    // 0 / 128
    const int wn = (w & 3) * 64;      // 0..192

    // --- staging addresses: inst = w*2+jj (0..15), 8 rows x 16B per inst ---
    const int gchunk = (l7 ^ l3) * 8;           // swizzled global chunk (elts)
    const int iA0 = w * 2, iA1 = w * 2 + 1;
    const int raA0 = (iA0 >> 3) * 128 + (iA0 & 7) * 8;
    const int raA1 = (iA1 >> 3) * 128 + (iA1 & 7) * 8;
    const int rbB0 = (iA0 >> 2) * 64 + (iA0 & 3) * 8;
    const int rbB1 = (iA1 >> 2) * 64 + (iA1 & 3) * 8;
    const unsigned short* pA0 = A  + (size_t)(bm + raA0 + l3) * K + gchunk;
    const unsigned short* pA1 = A  + (size_t)(bm + raA1 + l3) * K + gchunk;
    const unsigned short* pB0 = BT + (size_t)(bn + rbB0 + l3) * K + gchunk;
    const unsigned short* pB1 = BT + (size_t)(bn + rbB1 + l3) * K + gchunk;
    const int ldsA0 = raA0 * 64, ldsA1 = raA1 * 64;
    const int ldsB0 = rbB0 * 64, ldsB1 = rbB1 * 64;

    // --- fragment-read constants ---
    const int c0   = ((quad ^ l7) & 7) * 8;   // ks=0 phys chunk (ushort off)
    const int c1   = c0 ^ 32;                 // ks=1 (logical ^4 chunks)
    const int aRow = (wm + qcol) * 64;
    const int bRow = (wn + qcol) * 64;

    v4f acc[8][4];
#pragma unroll
    for (int i = 0; i < 8; i++)
#pragma unroll
        for (int j = 0; j < 4; j++) acc[i][j] = (v4f){0.f, 0.f, 0.f, 0.f};

    v8bf af[4][2];    // A frags of current mh (4 m-frags x 2 ksteps)
    v8bf bf2[2][2];   // B frags of current nh (2 n-frags x 2 ksteps)

    const int nt = K >> 6;   // K-tiles (BK=64); nt >= 2

    // --- prologue: tile0 all 4 groups + tile1 g0 groups (12 loads/wave) ---
    STAGE_A(0, 0, 0); STAGE_B(0, 0, 0);
    STAGE_A(0, 1, 0); STAGE_B(0, 1, 0);
    STAGE_A(1, 0, 1); STAGE_B(1, 0, 1);
    asm volatile("s_waitcnt vmcnt(4)");
    __builtin_amdgcn_sched_barrier(0);
    __builtin_amdgcn_s_barrier();

    for (int t = 0; t < nt; ++t) {
        const int buf = t & 1, nbuf = buf ^ 1;
        const unsigned short* sAb = &sA[buf * 16384];
        const unsigned short* sBb = &sB[buf * 16384];
        const bool st1 = (t + 1 < nt);
        const bool st2 = (t + 2 < nt);

        // p0: (mh0,nh0); stage Ag1(t+1)->nbuf
        PHASE(0, 0, 1, if (st1) STAGE_A(nbuf, 1, t + 1), );
        // p1: (mh0,nh1); stage Bg1(t+1)->nbuf  (af reused from p0)
        PHASE(0, 1, 0, if (st1) STAGE_B(nbuf, 1, t + 1), );
        // p2: (mh1,nh0); stage Ag0(t+2)->buf   (A g0 last read @p0, 2 bars ago)
        PHASE(1, 0, 1, if (st2) STAGE_A(buf, 0, t + 2), );
        // p3: (mh1,nh1); stage Bg0(t+2)->buf   (B g0 last read @p2)
        PHASE(1, 1, 0, if (st2) STAGE_B(buf, 0, t + 2),
              if (t < nt - 2) { asm volatile("s_waitcnt vmcnt(4)"); }
              else            { asm volatile("s_waitcnt vmcnt(0)"); }
              __builtin_amdgcn_sched_barrier(0));
    }

    // ---- epilogue ----
    if (vmode == 0) {
#pragma unroll
        for (int mi = 0; mi < 8; mi++)
#pragma unroll
            for (int nj = 0; nj < 4; nj++)
#pragma unroll
                for (int r = 0; r < 4; r++) {
                    int row = bm + wm + mi * 16 + quad * 4 + r;
                    int col = bn + wn + nj * 16 + qcol;
                    C[(size_t)row * N + col] = f2b(acc[mi][nj][r] * scale);
                }
    } else {
#pragma unroll
        for (int mi = 0; mi < 8; mi++)
#pragma unroll
            for (int nj = 0; nj < 4; nj++)
#pragma unroll
                for (int r = 0; r < 4; r++) {
                    int row = bm + wm + mi * 16 + quad * 4 + r;
                    int col = bn + wn + nj * 16 + qcol;
                    size_t idx = ((size_t)(row >> 10) * 2048 + col) * 1024 + (row & 1023);
                    C[idx] = f2b(acc[mi][nj][r] * scale);
                }
    }
}

// ---------------------------------------------------------------------------
// Flash attention v3: LDS-staged K/V shared by all 4 waves, GEMM-style
// 2-barrier K-loop with global_load_lds width=16, 64-key tiles.
//
// Swizzle: LDS rows have power-of-2 byte strides (K: 256B, V: 128B), so
// naive fragment reads would be 16-way bank-conflicted. We XOR-permute the
// 16B chunks on the GLOBAL side of the staging load (per-lane global
// addresses are unconstrained; LDS dest must stay uniform + lane*16):
//   sK[key][chunk c] = K[key][c ^ (key&15)]   (16 chunks of 16B per row)
//   sV[d][chunk c]   = V^T[d][c ^ (d&7)]      (8 chunks of 16B per row)
// Readers XOR the same way -> 2-way-max aliasing (free per m136).
// ---------------------------------------------------------------------------
__global__ __launch_bounds__(256, 4) void attn_kernel(const unsigned short* __restrict__ qh,
                                                      const unsigned short* __restrict__ kh,
                                                      const unsigned short* __restrict__ vt,
                                                      float* __restrict__ out) {
    __shared__ __align__(16) unsigned short sK[64 * 128];   // [key][d] 64 rows x 256B
    __shared__ __align__(16) unsigned short sV[128 * 64];   // [d][key] 128 rows x 128B

    int lane = threadIdx.x & 63, w = threadIdx.x >> 6;
    int b = blockIdx.z, h = blockIdx.y;
    int q0 = blockIdx.x * 64 + w * 16;
    int qcol = lane & 15, quad = lane >> 4;

    // Q fragments (B-operand of 16x16x32): n = q = lane&15, k = d
    const unsigned short* qp = qh + (size_t)(b * SS + q0 + qcol) * DD + h * DHD;
    v8bf bq[4];
#pragma unroll
    for (int kk = 0; kk < 4; kk++)
        bq[kk] = __builtin_bit_cast(v8bf, *(const v8s*)(qp + kk * 32 + quad * 8));

    // --- staging addresses (element offsets within current tile) ---
    int ko[4];
#pragma unroll
    for (int j = 0; j < 4; j++) {
        int key = w * 16 + j * 4 + (lane >> 4);
        ko[j] = key * DD + (((lane & 15) ^ (key & 15)) * 8);
    }
    int vo0 = (w * 32 + (lane >> 3)) * SS + (((lane & 7) ^ (lane >> 3)) * 8);

    const unsigned short* kcur = kh + (size_t)b * SS * DD + h * DHD;
    const unsigned short* vcur = vt + (size_t)(b * HH + h) * DHD * SS;
    unsigned short* kl0 = &sK[(w * 16) * 128];
    unsigned short* vl0 = &sV[(w * 32) * 64];

    float m_i = -1e30f, l_i = 0.f;
    v4f acc[8];
#pragma unroll
    for (int c = 0; c < 8; c++) acc[c] = (v4f){0.f, 0.f, 0.f, 0.f};

    for (int kb = 0; kb < SS; kb += 64) {
        __syncthreads();   // previous tile's LDS reads complete
#pragma unroll
        for (int j = 0; j < 4; j++)
            __builtin_amdgcn_global_load_lds((const GLOBAL_AS void*)(kcur + ko[j]),
                                             (LDS_AS void*)(kl0 + j * 4 * 128), 16, 0, 0);
#pragma unroll
        for (int j = 0; j < 4; j++)
            __builtin_amdgcn_global_load_lds((const GLOBAL_AS void*)(vcur + vo0 + j * 8 * SS),
                                             (LDS_AS void*)(vl0 + j * 8 * 64), 16, 0, 0);
        kcur += (size_t)64 * DD;
        vcur += 64;
        __syncthreads();   // staging drained

        // S^T = K.Q^T : 16 MFMA 16x16x32, fragments from swizzled sK
        v4f s[4];
#pragma unroll
        for (int kf = 0; kf < 4; kf++) {
            s[kf] = (v4f){0.f, 0.f, 0.f, 0.f};
#pragma unroll
            for (int kk = 0; kk < 4; kk++) {
                v8bf ak = __builtin_bit_cast(v8bf,
                    *(const v8s*)&sK[(kf * 16 + qcol) * 128 + (((kk * 4 + quad) ^ qcol) * 8)]);
                s[kf] = __builtin_amdgcn_mfma_f32_16x16x32_bf16(ak, bq[kk], s[kf], 0, 0, 0);
            }
        }

        // online softmax over 64 keys (base-2; log2(e) folded into qh scale)
        float mx = -1e30f;
#pragma unroll
        for (int kf = 0; kf < 4; kf++)
#pragma unroll
            for (int r = 0; r < 4; r++) mx = fmaxf(mx, s[kf][r]);
        mx = fmaxf(mx, __shfl_xor(mx, 16));
        mx = fmaxf(mx, __shfl_xor(mx, 32));
        float m_new = fmaxf(m_i, mx);
        float rs = 0.f;
        v4s p[4];
#pragma unroll
        for (int kf = 0; kf < 4; kf++)
#pragma unroll
            for (int r = 0; r < 4; r++) {
                float pf = exp2f(s[kf][r] - m_new);
                rs += pf;
                p[kf][r] = (short)f2b(pf);
            }
        rs += __shfl_xor(rs, 16);
        rs += __shfl_xor(rs, 32);
        float alpha = exp2f(m_i - m_new);
        l_i = l_i * alpha + rs;
        m_i = m_new;
#pragma unroll
        for (int c = 0; c < 8; c++) {
            acc[c][0] *= alpha; acc[c][1] *= alpha;
            acc[c][2] *= alpha; acc[c][3] *= alpha;
        }

        // PV: 32 MFMA 16x16x16, V fragments from swizzled sV
#pragma unroll
        for (int c = 0; c < 8; c++) {
            int row = (c * 16 + qcol) * 64;
#pragma unroll
            for (int kf = 0; kf < 4; kf++) {
                v4s av = *(const v4s*)&sV[row + (((kf * 2 + (quad >> 1)) ^ (qcol & 7)) * 8)
                                              + (quad & 1) * 4];
                acc[c] = __builtin_amdgcn_mfma_f32_16x16x16bf16_1k(av, p[kf], acc[c], 0, 0, 0);
            }
        }
    }

    float rl = 1.0f / l_i;
    float* op = out + (size_t)(b * SS + q0 + qcol) * DD + h * DHD;
#pragma unroll
    for (int c = 0; c < 8; c++)
#pragma unroll
        for (int r = 0; r < 4; r++)
            op[c * 16 + quad * 4 + r] = acc[c][r] * rl;
}

// ---------------------------------------------------------------------------
// Launch. ws layout (needs 136 MB):
//   abuf @ 0 MB (32) | wbuf @ 32 (8) | qh @ 40 (32) | kh @ 72 (32) | vt @ 104 (32)
// ---------------------------------------------------------------------------
extern "C" void kernel_launch(void* const* d_in, const int* in_sizes, int n_in,
                              void* d_out, int out_size, void* d_ws, size_t ws_size,
                              hipStream_t stream) {
    const float* ins[3]  = {(const float*)d_in[0], (const float*)d_in[1], (const float*)d_in[2]};
    const float* wins[3] = {(const float*)d_in[3], (const float*)d_in[4], (const float*)d_in[5]};
    char* ws = (char*)d_ws;
    unsigned short* abuf = (unsigned short*)(ws);
    unsigned short* wbuf = (unsigned short*)(ws + (size_t)32 * 1024 * 1024);
    unsigned short* qhb  = (unsigned short*)(ws + (size_t)40 * 1024 * 1024);
    unsigned short* khb  = (unsigned short*)(ws + (size_t)72 * 1024 * 1024);
    unsigned short* vtb  = (unsigned short*)(ws + (size_t)104 * 1024 * 1024);
    float* out = (float*)d_out;

    unsigned short* outs[3] = {qhb, khb, vtb};
    const float qscale = 0.12753139626246937f;  // log2(e)/sqrt(128)
    float scales[3] = {qscale, 1.f, 1.f};
    int   vmodes[3] = {0, 0, 1};

    const int M = BB * SS, N = DD, K = DD;
    const int grid = (M / 256) * (N / 256);   // 32*8 = 256 WGs = 1/CU

    for (int i = 0; i < 3; i++) {
        cvt_f32_bf16<<<dim3(4096), dim3(256), 0, stream>>>(ins[i], abuf, (BB * SS * DD) / 4);
        wtrans_kernel<<<dim3(32, 32), dim3(256), 0, stream>>>(wins[i], wbuf);
        gemm256<<<dim3(grid), dim3(512), 0, stream>>>(abuf, wbuf, outs[i],
                                                      scales[i], vmodes[i], M, N, K);
    }
    attn_kernel<<<dim3(SS / 64, HH, BB), dim3(256), 0, stream>>>(qhb, khb, vtb, out);
}

// Round 3
// 624.026 us; speedup vs baseline: 1.1293x; 1.0220x over previous
//
#include <hip/hip_runtime.h>
#include <hip/hip_bf16.h>
#include <math.h>

// Problem constants
#define BB 8
#define SS 1024
#define DD 2048
#define HH 16
#define DHD 128

typedef float  v4f  __attribute__((ext_vector_type(4)));
typedef short  v4s  __attribute__((ext_vector_type(4)));
typedef short  v8s  __attribute__((ext_vector_type(8)));
typedef __bf16 v8bf __attribute__((ext_vector_type(8)));

#define GLOBAL_AS __attribute__((address_space(1)))
#define LDS_AS    __attribute__((address_space(3)))

__device__ __forceinline__ unsigned short f2b(float f) {
    union { float f; unsigned int u; } x; x.f = f;
    unsigned int r = x.u + 0x7fffu + ((x.u >> 16) & 1u);  // RNE
    return (unsigned short)(r >> 16);
}

__device__ __forceinline__ v8bf ldsv8(const unsigned short* p) {
    return __builtin_bit_cast(v8bf, *(const v8s*)p);
}

// ---------------------------------------------------------------------------
// fp32 -> bf16 elementwise convert (memory-bound)
// ---------------------------------------------------------------------------
__global__ __launch_bounds__(256) void cvt_f32_bf16(const float* __restrict__ src,
                                                    unsigned short* __restrict__ dst,
                                                    int n4) {
    int i = blockIdx.x * blockDim.x + threadIdx.x;
    int stride = gridDim.x * blockDim.x;
    for (; i < n4; i += stride) {
        v4f f = ((const v4f*)src)[i];
        v4s o;
        o[0] = (short)f2b(f[0]); o[1] = (short)f2b(f[1]);
        o[2] = (short)f2b(f[2]); o[3] = (short)f2b(f[3]);
        ((v4s*)dst)[i] = o;
    }
}

// ---------------------------------------------------------------------------
// W (K x N fp32, row-major) -> WT (N x K bf16, row-major). LDS-tiled transpose.
// ---------------------------------------------------------------------------
__global__ __launch_bounds__(256) void wtrans_kernel(const float* __restrict__ W,
                                                     unsigned short* __restrict__ WT) {
    __shared__ float t[64][65];
    int nb = blockIdx.x * 64;
    int kb = blockIdx.y * 64;
    int tr = threadIdx.x >> 4;         // 0..15
    int tc = (threadIdx.x & 15) * 4;   // 0..60
#pragma unroll
    for (int i = 0; i < 4; i++) {
        int k = kb + tr + i * 16;
        v4f v = *(const v4f*)(W + (size_t)k * DD + nb + tc);
        t[tr + i * 16][tc + 0] = v[0];
        t[tr + i * 16][tc + 1] = v[1];
        t[tr + i * 16][tc + 2] = v[2];
        t[tr + i * 16][tc + 3] = v[3];
    }
    __syncthreads();
#pragma unroll
    for (int i = 0; i < 4; i++) {
        int n = nb + tr + i * 16;
        v4s o;
#pragma unroll
        for (int j = 0; j < 4; j++) o[j] = (short)f2b(t[tc + j][tr + i * 16]);
        *(v4s*)(WT + (size_t)n * DD + kb + tc) = o;
    }
}

// ---------------------------------------------------------------------------
// 256x256-tile, BK=64, 8-wave, double-buffered bf16 GEMM.
//   C[m][n] = sum_k A[m][k] * BT[n][k]
//
// Round-3 schedule: de-serialized phases.
//  - 4 phases/tile, C-quadrant order (0,0)->(0,1)->(1,1)->(1,0) (28 ds_reads).
//  - ONE barrier per phase (at phase end). No lgkmcnt(0) drains, no
//    sched_barrier(0): compiler interleaves ds_read waits with MFMA
//    (fine-grained lgkmcnt(N)), so read-drain overlaps MFMA.
//  - ALL stages target nbuf (tile t+1 data): p0:Ag0 p1:Bg0 p2:Bg1 p3:Ag1.
//    nbuf's old content (tile t-1) was fully consumed last tile, so stages
//    are region-safe with only the tile-boundary barrier.
//  - Counted vmcnt: vmcnt(4) at end of p0/p1/p3 (each retires exactly the
//    one 2-instr stage needed one phase later; >=3 phases latency cover).
//    Never drains to 0 except the peeled last tile (vmcnt(2)/vmcnt(0)).
//  - MFMA emitted as k0-pass then k1-pass: no dependent back-to-back pairs.
//
// Swizzle (verified round 1: SQ_LDS_BANK_CONFLICT = 0): LDS rows are 128B;
// 16B chunks XOR-permuted on the GLOBAL side of global_load_lds (LDS dest
// must stay linear): phys_chunk = logical ^ (row&7); readers same XOR.
//
// Grid map: XCD-chunked. XCD x (= bid%8) owns bm-panels [4x,4x+4) x all 8
// bn-panels: A fetched once per owning XCD (32MB total vs 256MB round-robin),
// B-panel shared by the 4 in-XCD blocks via L2.
// ---------------------------------------------------------------------------

#define STAGE_A(bb, gg, tt) do {                                              \
    __builtin_amdgcn_global_load_lds(                                         \
        (const GLOBAL_AS void*)(pA0 + (size_t)(gg) * 64 * K + (size_t)(tt) * 64), \
        (LDS_AS void*)(&sA[(bb) * 16384 + ldsA0 + (gg) * 4096]), 16, 0, 0);   \
    __builtin_amdgcn_global_load_lds(                                         \
        (const GLOBAL_AS void*)(pA1 + (size_t)(gg) * 64 * K + (size_t)(tt) * 64), \
        (LDS_AS void*)(&sA[(bb) * 16384 + ldsA1 + (gg) * 4096]), 16, 0, 0);   \
} while (0)

#define STAGE_B(bb, gg, tt) do {                                              \
    __builtin_amdgcn_global_load_lds(                                         \
        (const GLOBAL_AS void*)(pB0 + (size_t)(gg) * 32 * K + (size_t)(tt) * 64), \
        (LDS_AS void*)(&sB[(bb) * 16384 + ldsB0 + (gg) * 2048]), 16, 0, 0);   \
    __builtin_amdgcn_global_load_lds(                                         \
        (const GLOBAL_AS void*)(pB1 + (size_t)(gg) * 32 * K + (size_t)(tt) * 64), \
        (LDS_AS void*)(&sB[(bb) * 16384 + ldsB1 + (gg) * 2048]), 16, 0, 0);   \
} while (0)

// One phase: stage (issue-early), optional A/B fragment ds_reads, prio-raised
// MFMA quadrant (k0-pass then k1-pass), counted wait, ONE barrier.
// mh/nh/DOLDA/DOLDB are literal constants.
#define PHASE(mh, nh, DOLDA, DOLDB, STAGE_STMT, WAIT_STMT) do {               \
    STAGE_STMT;                                                               \
    if (DOLDA) {                                                              \
        _Pragma("unroll")                                                     \
        for (int i = 0; i < 4; i++) {                                         \
            af[i][0] = ldsv8(sAb + aRow + (mh) * 4096 + i * 1024 + c0);       \
            af[i][1] = ldsv8(sAb + aRow + (mh) * 4096 + i * 1024 + c1);       \
        }                                                                     \
    }                                                                         \
    if (DOLDB) {                                                              \
        _Pragma("unroll")                                                     \
        for (int j = 0; j < 2; j++) {                                         \
            bf2[j][0] = ldsv8(sBb + bRow + (nh) * 2048 + j * 1024 + c0);      \
            bf2[j][1] = ldsv8(sBb + bRow + (nh) * 2048 + j * 1024 + c1);      \
        }                                                                     \
    }                                                                         \
    __builtin_amdgcn_s_setprio(1);                                            \
    _Pragma("unroll")                                                         \
    for (int i = 0; i < 4; i++) {                                             \
        _Pragma("unroll")                                                     \
        for (int j = 0; j < 2; j++)                                           \
            acc[(mh) * 4 + i][(nh) * 2 + j] =                                 \
                __builtin_amdgcn_mfma_f32_16x16x32_bf16(                      \
                    af[i][0], bf2[j][0], acc[(mh) * 4 + i][(nh) * 2 + j], 0, 0, 0); \
    }                                                                         \
    _Pragma("unroll")                                                         \
    for (int i = 0; i < 4; i++) {                                             \
        _Pragma("unroll")                                                     \
        for (int j = 0; j < 2; j++)                                           \
            acc[(mh) * 4 + i][(nh) * 2 + j] =                                 \
                __builtin_amdgcn_mfma_f32_16x16x32_bf16(                      \
                    af[i][1], bf2[j][1], acc[(mh) * 4 + i][(nh) * 2 + j], 0, 0, 0); \
    }                                                                         \
    __builtin_amdgcn_s_setprio(0);                                            \
    WAIT_STMT;                                                                \
    __builtin_amdgcn_s_barrier();                                             \
} while (0)

__global__ __launch_bounds__(512, 2) void gemm256(const unsigned short* __restrict__ A,
                                                  const unsigned short* __restrict__ BT,
                                                  unsigned short* __restrict__ C,
                                                  float scale, int vmode,
                                                  int M, int N, int K) {
    __shared__ __align__(16) unsigned short sA[2 * 16384];   // 2 x 256 x 64
    __shared__ __align__(16) unsigned short sB[2 * 16384];

    const int tid  = threadIdx.x;
    const int lane = tid & 63;
    const int w    = tid >> 6;        // 0..7
    const int qcol = lane & 15;
    const int quad = lane >> 4;
    const int l3   = lane >> 3;       // 0..7 row-within-8 for staging
    const int l7   = lane & 7;

    // XCD-chunked grid map: XCD x = bid%8 owns bm-panels [4x,4x+4) x all bn.
    const int bid = blockIdx.x;
    const int bm  = ((bid & 7) * 4 + ((bid >> 3) & 3)) * 256;
    const int bn  = (bid >> 5) * 256;

    const int wm = (w >> 2) * 128;    // 0 / 128
    const int wn = (w & 3) * 64;      // 0..192

    // --- staging addresses: inst = w*2+jj (0..15), 8 rows x 16B per inst ---
    const int gchunk = (l7 ^ l3) * 8;           // swizzled global chunk (elts)
    const int iA0 = w * 2, iA1 = w * 2 + 1;
    const int raA0 = (iA0 >> 3) * 128 + (iA0 & 7) * 8;
    const int raA1 = (iA1 >> 3) * 128 + (iA1 & 7) * 8;
    const int rbB0 = (iA0 >> 2) * 64 + (iA0 & 3) * 8;
    const int rbB1 = (iA1 >> 2) * 64 + (iA1 & 3) * 8;
    const unsigned short* pA0 = A  + (size_t)(bm + raA0 + l3) * K + gchunk;
    const unsigned short* pA1 = A  + (size_t)(bm + raA1 + l3) * K + gchunk;
    const unsigned short* pB0 = BT + (size_t)(bn + rbB0 + l3) * K + gchunk;
    const unsigned short* pB1 = BT + (size_t)(bn + rbB1 + l3) * K + gchunk;
    const int ldsA0 = raA0 * 64, ldsA1 = raA1 * 64;
    const int ldsB0 = rbB0 * 64, ldsB1 = rbB1 * 64;

    // --- fragment-read constants ---
    const int c0   = ((quad ^ l7) & 7) * 8;   // ks=0 phys chunk (ushort off)
    const int c1   = c0 ^ 32;                 // ks=1 (logical ^4 chunks)
    const int aRow = (wm + qcol) * 64;
    const int bRow = (wn + qcol) * 64;

    v4f acc[8][4];
#pragma unroll
    for (int i = 0; i < 8; i++)
#pragma unroll
        for (int j = 0; j < 4; j++) acc[i][j] = (v4f){0.f, 0.f, 0.f, 0.f};

    v8bf af[4][2];    // A frags of current mh (4 m-frags x 2 ksteps)
    v8bf bf2[2][2];   // B frags of current nh (2 n-frags x 2 ksteps)

    const int nt = K >> 6;   // K-tiles (BK=64); nt >= 2

    // --- prologue: tile0 all 4 groups in p0-consumption order ---
    STAGE_A(0, 0, 0);   // Ag0(t0)
    STAGE_B(0, 0, 0);   // Bg0(t0)
    STAGE_B(0, 1, 0);   // Bg1(t0)
    STAGE_A(0, 1, 0);   // Ag1(t0)
    asm volatile("s_waitcnt vmcnt(4)");   // retire Ag0,Bg0
    __builtin_amdgcn_s_barrier();

    for (int t = 0; t < nt - 1; ++t) {
        const int buf = t & 1, nbuf = buf ^ 1;
        const unsigned short* sAb = &sA[buf * 16384];
        const unsigned short* sBb = &sB[buf * 16384];

        // p0: (0,0); stage Ag0(t+1); retire Bg1(t) [staged prev p2]
        PHASE(0, 0, 1, 1, STAGE_A(nbuf, 0, t + 1),
              asm volatile("s_waitcnt vmcnt(4)"));
        // p1: (0,1); stage Bg0(t+1); retire Ag1(t) [staged prev p3]
        PHASE(0, 1, 0, 1, STAGE_B(nbuf, 0, t + 1),
              asm volatile("s_waitcnt vmcnt(4)"));
        // p2: (1,1); stage Bg1(t+1); no wait (bf2 kept from p1)
        PHASE(1, 1, 1, 0, STAGE_B(nbuf, 1, t + 1), );
        // p3: (1,0); stage Ag1(t+1); retire Ag0,Bg0(t+1) [this tile p0,p1]
        PHASE(1, 0, 0, 1, STAGE_A(nbuf, 1, t + 1),
              asm volatile("s_waitcnt vmcnt(4)"));
    }

    // --- peeled last tile: no stages; drain remaining prefetches ---
    {
        const int buf = (nt - 1) & 1;
        const unsigned short* sAb = &sA[buf * 16384];
        const unsigned short* sBb = &sB[buf * 16384];
        PHASE(0, 0, 1, 1, , asm volatile("s_waitcnt vmcnt(2)"));  // Bg1 ready
        PHASE(0, 1, 0, 1, , asm volatile("s_waitcnt vmcnt(0)"));  // Ag1 ready
        PHASE(1, 1, 1, 0, , );
        PHASE(1, 0, 0, 1, , );
    }

    // ---- epilogue ----
    if (vmode == 0) {
#pragma unroll
        for (int mi = 0; mi < 8; mi++)
#pragma unroll
            for (int nj = 0; nj < 4; nj++)
#pragma unroll
                for (int r = 0; r < 4; r++) {
                    int row = bm + wm + mi * 16 + quad * 4 + r;
                    int col = bn + wn + nj * 16 + qcol;
                    C[(size_t)row * N + col] = f2b(acc[mi][nj][r] * scale);
                }
    } else {
#pragma unroll
        for (int mi = 0; mi < 8; mi++)
#pragma unroll
            for (int nj = 0; nj < 4; nj++)
#pragma unroll
                for (int r = 0; r < 4; r++) {
                    int row = bm + wm + mi * 16 + quad * 4 + r;
                    int col = bn + wn + nj * 16 + qcol;
                    size_t idx = ((size_t)(row >> 10) * 2048 + col) * 1024 + (row & 1023);
                    C[idx] = f2b(acc[mi][nj][r] * scale);
                }
    }
}

// ---------------------------------------------------------------------------
// Flash attention v3: LDS-staged K/V shared by all 4 waves, GEMM-style
// 2-barrier K-loop with global_load_lds width=16, 64-key tiles.
//
// Swizzle: LDS rows have power-of-2 byte strides (K: 256B, V: 128B), so
// naive fragment reads would be 16-way bank-conflicted. We XOR-permute the
// 16B chunks on the GLOBAL side of the staging load (per-lane global
// addresses are unconstrained; LDS dest must stay uniform + lane*16):
//   sK[key][chunk c] = K[key][c ^ (key&15)]   (16 chunks of 16B per row)
//   sV[d][chunk c]   = V^T[d][c ^ (d&7)]      (8 chunks of 16B per row)
// Readers XOR the same way -> 2-way-max aliasing (free per m136).
// ---------------------------------------------------------------------------
__global__ __launch_bounds__(256, 4) void attn_kernel(const unsigned short* __restrict__ qh,
                                                      const unsigned short* __restrict__ kh,
                                                      const unsigned short* __restrict__ vt,
                                                      float* __restrict__ out) {
    __shared__ __align__(16) unsigned short sK[64 * 128];   // [key][d] 64 rows x 256B
    __shared__ __align__(16) unsigned short sV[128 * 64];   // [d][key] 128 rows x 128B

    int lane = threadIdx.x & 63, w = threadIdx.x >> 6;
    int b = blockIdx.z, h = blockIdx.y;
    int q0 = blockIdx.x * 64 + w * 16;
    int qcol = lane & 15, quad = lane >> 4;

    // Q fragments (B-operand of 16x16x32): n = q = lane&15, k = d
    const unsigned short* qp = qh + (size_t)(b * SS + q0 + qcol) * DD + h * DHD;
    v8bf bq[4];
#pragma unroll
    for (int kk = 0; kk < 4; kk++)
        bq[kk] = __builtin_bit_cast(v8bf, *(const v8s*)(qp + kk * 32 + quad * 8));

    // --- staging addresses (element offsets within current tile) ---
    int ko[4];
#pragma unroll
    for (int j = 0; j < 4; j++) {
        int key = w * 16 + j * 4 + (lane >> 4);
        ko[j] = key * DD + (((lane & 15) ^ (key & 15)) * 8);
    }
    int vo0 = (w * 32 + (lane >> 3)) * SS + (((lane & 7) ^ (lane >> 3)) * 8);

    const unsigned short* kcur = kh + (size_t)b * SS * DD + h * DHD;
    const unsigned short* vcur = vt + (size_t)(b * HH + h) * DHD * SS;
    unsigned short* kl0 = &sK[(w * 16) * 128];
    unsigned short* vl0 = &sV[(w * 32) * 64];

    float m_i = -1e30f, l_i = 0.f;
    v4f acc[8];
#pragma unroll
    for (int c = 0; c < 8; c++) acc[c] = (v4f){0.f, 0.f, 0.f, 0.f};

    for (int kb = 0; kb < SS; kb += 64) {
        __syncthreads();   // previous tile's LDS reads complete
#pragma unroll
        for (int j = 0; j < 4; j++)
            __builtin_amdgcn_global_load_lds((const GLOBAL_AS void*)(kcur + ko[j]),
                                             (LDS_AS void*)(kl0 + j * 4 * 128), 16, 0, 0);
#pragma unroll
        for (int j = 0; j < 4; j++)
            __builtin_amdgcn_global_load_lds((const GLOBAL_AS void*)(vcur + vo0 + j * 8 * SS),
                                             (LDS_AS void*)(vl0 + j * 8 * 64), 16, 0, 0);
        kcur += (size_t)64 * DD;
        vcur += 64;
        __syncthreads();   // staging drained

        // S^T = K.Q^T : 16 MFMA 16x16x32, fragments from swizzled sK
        v4f s[4];
#pragma unroll
        for (int kf = 0; kf < 4; kf++) {
            s[kf] = (v4f){0.f, 0.f, 0.f, 0.f};
#pragma unroll
            for (int kk = 0; kk < 4; kk++) {
                v8bf ak = __builtin_bit_cast(v8bf,
                    *(const v8s*)&sK[(kf * 16 + qcol) * 128 + (((kk * 4 + quad) ^ qcol) * 8)]);
                s[kf] = __builtin_amdgcn_mfma_f32_16x16x32_bf16(ak, bq[kk], s[kf], 0, 0, 0);
            }
        }

        // online softmax over 64 keys (base-2; log2(e) folded into qh scale)
        float mx = -1e30f;
#pragma unroll
        for (int kf = 0; kf < 4; kf++)
#pragma unroll
            for (int r = 0; r < 4; r++) mx = fmaxf(mx, s[kf][r]);
        mx = fmaxf(mx, __shfl_xor(mx, 16));
        mx = fmaxf(mx, __shfl_xor(mx, 32));
        float m_new = fmaxf(m_i, mx);
        float rs = 0.f;
        v4s p[4];
#pragma unroll
        for (int kf = 0; kf < 4; kf++)
#pragma unroll
            for (int r = 0; r < 4; r++) {
                float pf = exp2f(s[kf][r] - m_new);
                rs += pf;
                p[kf][r] = (short)f2b(pf);
            }
        rs += __shfl_xor(rs, 16);
        rs += __shfl_xor(rs, 32);
        float alpha = exp2f(m_i - m_new);
        l_i = l_i * alpha + rs;
        m_i = m_new;
#pragma unroll
        for (int c = 0; c < 8; c++) {
            acc[c][0] *= alpha; acc[c][1] *= alpha;
            acc[c][2] *= alpha; acc[c][3] *= alpha;
        }

        // PV: 32 MFMA 16x16x16, V fragments from swizzled sV
#pragma unroll
        for (int c = 0; c < 8; c++) {
            int row = (c * 16 + qcol) * 64;
#pragma unroll
            for (int kf = 0; kf < 4; kf++) {
                v4s av = *(const v4s*)&sV[row + (((kf * 2 + (quad >> 1)) ^ (qcol & 7)) * 8)
                                              + (quad & 1) * 4];
                acc[c] = __builtin_amdgcn_mfma_f32_16x16x16bf16_1k(av, p[kf], acc[c], 0, 0, 0);
            }
        }
    }

    float rl = 1.0f / l_i;
    float* op = out + (size_t)(b * SS + q0 + qcol) * DD + h * DHD;
#pragma unroll
    for (int c = 0; c < 8; c++)
#pragma unroll
        for (int r = 0; r < 4; r++)
            op[c * 16 + quad * 4 + r] = acc[c][r] * rl;
}

// ---------------------------------------------------------------------------
// Launch. ws layout (needs 136 MB):
//   abuf @ 0 MB (32) | wbuf @ 32 (8) | qh @ 40 (32) | kh @ 72 (32) | vt @ 104 (32)
// ---------------------------------------------------------------------------
extern "C" void kernel_launch(void* const* d_in, const int* in_sizes, int n_in,
                              void* d_out, int out_size, void* d_ws, size_t ws_size,
                              hipStream_t stream) {
    const float* ins[3]  = {(const float*)d_in[0], (const float*)d_in[1], (const float*)d_in[2]};
    const float* wins[3] = {(const float*)d_in[3], (const float*)d_in[4], (const float*)d_in[5]};
    char* ws = (char*)d_ws;
    unsigned short* abuf = (unsigned short*)(ws);
    unsigned short* wbuf = (unsigned short*)(ws + (size_t)32 * 1024 * 1024);
    unsigned short* qhb  = (unsigned short*)(ws + (size_t)40 * 1024 * 1024);
    unsigned short* khb  = (unsigned short*)(ws + (size_t)72 * 1024 * 1024);
    unsigned short* vtb  = (unsigned short*)(ws + (size_t)104 * 1024 * 1024);
    float* out = (float*)d_out;

    unsigned short* outs[3] = {qhb, khb, vtb};
    const float qscale = 0.12753139626246937f;  // log2(e)/sqrt(128)
    float scales[3] = {qscale, 1.f, 1.f};
    int   vmodes[3] = {0, 0, 1};

    const int M = BB * SS, N = DD, K = DD;
    const int grid = (M / 256) * (N / 256);   // 32*8 = 256 WGs = 1/CU

    for (int i = 0; i < 3; i++) {
        cvt_f32_bf16<<<dim3(4096), dim3(256), 0, stream>>>(ins[i], abuf, (BB * SS * DD) / 4);
        wtrans_kernel<<<dim3(32, 32), dim3(256), 0, stream>>>(wins[i], wbuf);
        gemm256<<<dim3(grid), dim3(512), 0, stream>>>(abuf, wbuf, outs[i],
                                                      scales[i], vmodes[i], M, N, K);
    }
    attn_kernel<<<dim3(SS / 64, HH, BB), dim3(256), 0, stream>>>(qhb, khb, vtb, out);
}

// Round 4
// 584.304 us; speedup vs baseline: 1.2060x; 1.0680x over previous
//
#include <hip/hip_runtime.h>
#include <hip/hip_bf16.h>
#include <math.h>

// Problem constants
#define BB 8
#define SS 1024
#define DD 2048
#define HH 16
#define DHD 128

typedef float  v4f  __attribute__((ext_vector_type(4)));
typedef short  v4s  __attribute__((ext_vector_type(4)));
typedef short  v8s  __attribute__((ext_vector_type(8)));
typedef __bf16 v8bf __attribute__((ext_vector_type(8)));

#define GLOBAL_AS __attribute__((address_space(1)))
#define LDS_AS    __attribute__((address_space(3)))

__device__ __forceinline__ unsigned short f2b(float f) {
    union { float f; unsigned int u; } x; x.f = f;
    unsigned int r = x.u + 0x7fffu + ((x.u >> 16) & 1u);  // RNE
    return (unsigned short)(r >> 16);
}

__device__ __forceinline__ v8bf ldsv8(const unsigned short* p) {
    return __builtin_bit_cast(v8bf, *(const v8s*)p);
}

// ---------------------------------------------------------------------------
// fp32 -> bf16 elementwise convert (memory-bound)
// ---------------------------------------------------------------------------
__global__ __launch_bounds__(256) void cvt_f32_bf16(const float* __restrict__ src,
                                                    unsigned short* __restrict__ dst,
                                                    int n4) {
    int i = blockIdx.x * blockDim.x + threadIdx.x;
    int stride = gridDim.x * blockDim.x;
    for (; i < n4; i += stride) {
        v4f f = ((const v4f*)src)[i];
        v4s o;
        o[0] = (short)f2b(f[0]); o[1] = (short)f2b(f[1]);
        o[2] = (short)f2b(f[2]); o[3] = (short)f2b(f[3]);
        ((v4s*)dst)[i] = o;
    }
}

// ---------------------------------------------------------------------------
// W (K x N fp32, row-major) -> WT (N x K bf16, row-major). LDS-tiled transpose.
// ---------------------------------------------------------------------------
__global__ __launch_bounds__(256) void wtrans_kernel(const float* __restrict__ W,
                                                     unsigned short* __restrict__ WT) {
    __shared__ float t[64][65];
    int nb = blockIdx.x * 64;
    int kb = blockIdx.y * 64;
    int tr = threadIdx.x >> 4;         // 0..15
    int tc = (threadIdx.x & 15) * 4;   // 0..60
#pragma unroll
    for (int i = 0; i < 4; i++) {
        int k = kb + tr + i * 16;
        v4f v = *(const v4f*)(W + (size_t)k * DD + nb + tc);
        t[tr + i * 16][tc + 0] = v[0];
        t[tr + i * 16][tc + 1] = v[1];
        t[tr + i * 16][tc + 2] = v[2];
        t[tr + i * 16][tc + 3] = v[3];
    }
    __syncthreads();
#pragma unroll
    for (int i = 0; i < 4; i++) {
        int n = nb + tr + i * 16;
        v4s o;
#pragma unroll
        for (int j = 0; j < 4; j++) o[j] = (short)f2b(t[tc + j][tr + i * 16]);
        *(v4s*)(WT + (size_t)n * DD + kb + tc) = o;
    }
}

// ---------------------------------------------------------------------------
// 256x256-tile, BK=64, 8-wave, double-buffered bf16 GEMM.
//   C[m][n] = sum_k A[m][k] * BT[n][k]
//
// Round-4 delta vs round-3: setprio REMOVED (m190: setprio hurts lockstep
// barrier structures; with 2 waves/SIMD it serializes the SIMD's waves).
// Everything else frozen so next round's counters describe this kernel.
//
// Schedule (round 3): 4 phases/tile, quadrant order (0,0)->(0,1)->(1,1)->
// (1,0); ONE barrier per phase; all stages target nbuf (t+1); counted
// vmcnt(4), drained only in the peeled last tile.
//
// Swizzle (verified: SQ_LDS_BANK_CONFLICT = 0): LDS rows 128B; 16B chunks
// XOR-permuted on the GLOBAL side of global_load_lds (LDS dest stays
// linear): phys_chunk = logical ^ (row&7); readers same XOR.
//
// Grid map: XCD-chunked. XCD x (= bid%8) owns bm-panels [4x,4x+4) x all 8
// bn-panels.
// ---------------------------------------------------------------------------

#define STAGE_A(bb, gg, tt) do {                                              \
    __builtin_amdgcn_global_load_lds(                                         \
        (const GLOBAL_AS void*)(pA0 + (size_t)(gg) * 64 * K + (size_t)(tt) * 64), \
        (LDS_AS void*)(&sA[(bb) * 16384 + ldsA0 + (gg) * 4096]), 16, 0, 0);   \
    __builtin_amdgcn_global_load_lds(                                         \
        (const GLOBAL_AS void*)(pA1 + (size_t)(gg) * 64 * K + (size_t)(tt) * 64), \
        (LDS_AS void*)(&sA[(bb) * 16384 + ldsA1 + (gg) * 4096]), 16, 0, 0);   \
} while (0)

#define STAGE_B(bb, gg, tt) do {                                              \
    __builtin_amdgcn_global_load_lds(                                         \
        (const GLOBAL_AS void*)(pB0 + (size_t)(gg) * 32 * K + (size_t)(tt) * 64), \
        (LDS_AS void*)(&sB[(bb) * 16384 + ldsB0 + (gg) * 2048]), 16, 0, 0);   \
    __builtin_amdgcn_global_load_lds(                                         \
        (const GLOBAL_AS void*)(pB1 + (size_t)(gg) * 32 * K + (size_t)(tt) * 64), \
        (LDS_AS void*)(&sB[(bb) * 16384 + ldsB1 + (gg) * 2048]), 16, 0, 0);   \
} while (0)

// One phase: stage (issue-early), optional A/B fragment ds_reads, MFMA
// quadrant (k0-pass then k1-pass), counted wait, ONE barrier.
#define PHASE(mh, nh, DOLDA, DOLDB, STAGE_STMT, WAIT_STMT) do {               \
    STAGE_STMT;                                                               \
    if (DOLDA) {                                                              \
        _Pragma("unroll")                                                     \
        for (int i = 0; i < 4; i++) {                                         \
            af[i][0] = ldsv8(sAb + aRow + (mh) * 4096 + i * 1024 + c0);       \
            af[i][1] = ldsv8(sAb + aRow + (mh) * 4096 + i * 1024 + c1);       \
        }                                                                     \
    }                                                                         \
    if (DOLDB) {                                                              \
        _Pragma("unroll")                                                     \
        for (int j = 0; j < 2; j++) {                                         \
            bf2[j][0] = ldsv8(sBb + bRow + (nh) * 2048 + j * 1024 + c0);      \
            bf2[j][1] = ldsv8(sBb + bRow + (nh) * 2048 + j * 1024 + c1);      \
        }                                                                     \
    }                                                                         \
    _Pragma("unroll")                                                         \
    for (int i = 0; i < 4; i++) {                                             \
        _Pragma("unroll")                                                     \
        for (int j = 0; j < 2; j++)                                           \
            acc[(mh) * 4 + i][(nh) * 2 + j] =                                 \
                __builtin_amdgcn_mfma_f32_16x16x32_bf16(                      \
                    af[i][0], bf2[j][0], acc[(mh) * 4 + i][(nh) * 2 + j], 0, 0, 0); \
    }                                                                         \
    _Pragma("unroll")                                                         \
    for (int i = 0; i < 4; i++) {                                             \
        _Pragma("unroll")                                                     \
        for (int j = 0; j < 2; j++)                                           \
            acc[(mh) * 4 + i][(nh) * 2 + j] =                                 \
                __builtin_amdgcn_mfma_f32_16x16x32_bf16(                      \
                    af[i][1], bf2[j][1], acc[(mh) * 4 + i][(nh) * 2 + j], 0, 0, 0); \
    }                                                                         \
    WAIT_STMT;                                                                \
    __builtin_amdgcn_s_barrier();                                             \
} while (0)

__global__ __launch_bounds__(512, 2) void gemm256(const unsigned short* __restrict__ A,
                                                  const unsigned short* __restrict__ BT,
                                                  unsigned short* __restrict__ C,
                                                  float scale, int vmode,
                                                  int M, int N, int K) {
    __shared__ __align__(16) unsigned short sA[2 * 16384];   // 2 x 256 x 64
    __shared__ __align__(16) unsigned short sB[2 * 16384];

    const int tid  = threadIdx.x;
    const int lane = tid & 63;
    const int w    = tid >> 6;        // 0..7
    const int qcol = lane & 15;
    const int quad = lane >> 4;
    const int l3   = lane >> 3;       // 0..7 row-within-8 for staging
    const int l7   = lane & 7;

    // XCD-chunked grid map: XCD x = bid%8 owns bm-panels [4x,4x+4) x all bn.
    const int bid = blockIdx.x;
    const int bm  = ((bid & 7) * 4 + ((bid >> 3) & 3)) * 256;
    const int bn  = (bid >> 5) * 256;

    const int wm = (w >> 2) * 128;    // 0 / 128
    const int wn = (w & 3) * 64;      // 0..192

    // --- staging addresses: inst = w*2+jj (0..15), 8 rows x 16B per inst ---
    const int gchunk = (l7 ^ l3) * 8;           // swizzled global chunk (elts)
    const int iA0 = w * 2, iA1 = w * 2 + 1;
    const int raA0 = (iA0 >> 3) * 128 + (iA0 & 7) * 8;
    const int raA1 = (iA1 >> 3) * 128 + (iA1 & 7) * 8;
    const int rbB0 = (iA0 >> 2) * 64 + (iA0 & 3) * 8;
    const int rbB1 = (iA1 >> 2) * 64 + (iA1 & 3) * 8;
    const unsigned short* pA0 = A  + (size_t)(bm + raA0 + l3) * K + gchunk;
    const unsigned short* pA1 = A  + (size_t)(bm + raA1 + l3) * K + gchunk;
    const unsigned short* pB0 = BT + (size_t)(bn + rbB0 + l3) * K + gchunk;
    const unsigned short* pB1 = BT + (size_t)(bn + rbB1 + l3) * K + gchunk;
    const int ldsA0 = raA0 * 64, ldsA1 = raA1 * 64;
    const int ldsB0 = rbB0 * 64, ldsB1 = rbB1 * 64;

    // --- fragment-read constants ---
    const int c0   = ((quad ^ l7) & 7) * 8;   // ks=0 phys chunk (ushort off)
    const int c1   = c0 ^ 32;                 // ks=1 (logical ^4 chunks)
    const int aRow = (wm + qcol) * 64;
    const int bRow = (wn + qcol) * 64;

    v4f acc[8][4];
#pragma unroll
    for (int i = 0; i < 8; i++)
#pragma unroll
        for (int j = 0; j < 4; j++) acc[i][j] = (v4f){0.f, 0.f, 0.f, 0.f};

    v8bf af[4][2];    // A frags of current mh (4 m-frags x 2 ksteps)
    v8bf bf2[2][2];   // B frags of current nh (2 n-frags x 2 ksteps)

    const int nt = K >> 6;   // K-tiles (BK=64); nt >= 2

    // --- prologue: tile0 all 4 groups in p0-consumption order ---
    STAGE_A(0, 0, 0);   // Ag0(t0)
    STAGE_B(0, 0, 0);   // Bg0(t0)
    STAGE_B(0, 1, 0);   // Bg1(t0)
    STAGE_A(0, 1, 0);   // Ag1(t0)
    asm volatile("s_waitcnt vmcnt(4)");   // retire Ag0,Bg0
    __builtin_amdgcn_s_barrier();

    for (int t = 0; t < nt - 1; ++t) {
        const int buf = t & 1, nbuf = buf ^ 1;
        const unsigned short* sAb = &sA[buf * 16384];
        const unsigned short* sBb = &sB[buf * 16384];

        // p0: (0,0); stage Ag0(t+1); retire Bg1(t) [staged prev p2]
        PHASE(0, 0, 1, 1, STAGE_A(nbuf, 0, t + 1),
              asm volatile("s_waitcnt vmcnt(4)"));
        // p1: (0,1); stage Bg0(t+1); retire Ag1(t) [staged prev p3]
        PHASE(0, 1, 0, 1, STAGE_B(nbuf, 0, t + 1),
              asm volatile("s_waitcnt vmcnt(4)"));
        // p2: (1,1); stage Bg1(t+1); no wait (bf2 kept from p1)
        PHASE(1, 1, 1, 0, STAGE_B(nbuf, 1, t + 1), );
        // p3: (1,0); stage Ag1(t+1); retire Ag0,Bg0(t+1) [this tile p0,p1]
        PHASE(1, 0, 0, 1, STAGE_A(nbuf, 1, t + 1),
              asm volatile("s_waitcnt vmcnt(4)"));
    }

    // --- peeled last tile: no stages; drain remaining prefetches ---
    {
        const int buf = (nt - 1) & 1;
        const unsigned short* sAb = &sA[buf * 16384];
        const unsigned short* sBb = &sB[buf * 16384];
        PHASE(0, 0, 1, 1, , asm volatile("s_waitcnt vmcnt(2)"));  // Bg1 ready
        PHASE(0, 1, 0, 1, , asm volatile("s_waitcnt vmcnt(0)"));  // Ag1 ready
        PHASE(1, 1, 1, 0, , );
        PHASE(1, 0, 0, 1, , );
    }

    // ---- epilogue ----
    if (vmode == 0) {
#pragma unroll
        for (int mi = 0; mi < 8; mi++)
#pragma unroll
            for (int nj = 0; nj < 4; nj++)
#pragma unroll
                for (int r = 0; r < 4; r++) {
                    int row = bm + wm + mi * 16 + quad * 4 + r;
                    int col = bn + wn + nj * 16 + qcol;
                    C[(size_t)row * N + col] = f2b(acc[mi][nj][r] * scale);
                }
    } else {
#pragma unroll
        for (int mi = 0; mi < 8; mi++)
#pragma unroll
            for (int nj = 0; nj < 4; nj++)
#pragma unroll
                for (int r = 0; r < 4; r++) {
                    int row = bm + wm + mi * 16 + quad * 4 + r;
                    int col = bn + wn + nj * 16 + qcol;
                    size_t idx = ((size_t)(row >> 10) * 2048 + col) * 1024 + (row & 1023);
                    C[idx] = f2b(acc[mi][nj][r] * scale);
                }
    }
}

// ---------------------------------------------------------------------------
// Flash attention v4: PV upgraded from 32x mfma_16x16x16 to 16x mfma_16x16x32
// by routing P through a per-wave LDS slice (sP, 2 KB/wave):
//  - After softmax, lane holds P for q=qcol, keys kf*16+quad*4+r. Write as
//    4x b64 into sP[q][key] (16B chunks XOR-swizzled by q&7, mirroring sV).
//  - Read back 2x b128 in the x32 B-operand layout (keys ks*32+quad*8+j).
//  - V fragments become 16x b128 (A-operand x32: sV[d=c*16+qcol]
//    [keys ks*32+quad*8..+7]) instead of 32x 4-way-conflicted b64:
//    8 lanes/phys-chunk uniform -> bank floor.
// Same-wave sP write->read: true address aliases exist, so the compiler must
// (and does) order them with lgkmcnt.
// Skip-rescale: if no lane's max grew (__any gate), skip the O(acc) rescale.
// exp2f(0)=1 exactly -> bit-identical math.
// LDS: 16K (sK) + 16K (sV) + 8K (sP) = 40 KB -> still 4 blocks/CU.
//
// K/V staging swizzle unchanged (global-side XOR, LDS dest linear):
//   sK[key][chunk c] = K[key][c ^ (key&15)]   (16 chunks of 16B per row)
//   sV[d][chunk c]   = V^T[d][c ^ (d&7)]      (8 chunks of 16B per row)
// ---------------------------------------------------------------------------
__global__ __launch_bounds__(256, 4) void attn_kernel(const unsigned short* __restrict__ qh,
                                                      const unsigned short* __restrict__ kh,
                                                      const unsigned short* __restrict__ vt,
                                                      float* __restrict__ out) {
    __shared__ __align__(16) unsigned short sK[64 * 128];   // [key][d] 64 rows x 256B
    __shared__ __align__(16) unsigned short sV[128 * 64];   // [d][key] 128 rows x 128B
    __shared__ __align__(16) unsigned short sP[4 * 16 * 64]; // per-wave [q][key]

    int lane = threadIdx.x & 63, w = threadIdx.x >> 6;
    int b = blockIdx.z, h = blockIdx.y;
    int q0 = blockIdx.x * 64 + w * 16;
    int qcol = lane & 15, quad = lane >> 4;

    // Q fragments (B-operand of 16x16x32): n = q = lane&15, k = d
    const unsigned short* qp = qh + (size_t)(b * SS + q0 + qcol) * DD + h * DHD;
    v8bf bq[4];
#pragma unroll
    for (int kk = 0; kk < 4; kk++)
        bq[kk] = __builtin_bit_cast(v8bf, *(const v8s*)(qp + kk * 32 + quad * 8));

    // --- staging addresses (element offsets within current tile) ---
    int ko[4];
#pragma unroll
    for (int j = 0; j < 4; j++) {
        int key = w * 16 + j * 4 + (lane >> 4);
        ko[j] = key * DD + (((lane & 15) ^ (key & 15)) * 8);
    }
    int vo0 = (w * 32 + (lane >> 3)) * SS + (((lane & 7) ^ (lane >> 3)) * 8);

    const unsigned short* kcur = kh + (size_t)b * SS * DD + h * DHD;
    const unsigned short* vcur = vt + (size_t)(b * HH + h) * DHD * SS;
    unsigned short* kl0 = &sK[(w * 16) * 128];
    unsigned short* vl0 = &sV[(w * 32) * 64];
    unsigned short* sPw = &sP[w * 1024];

    // P LDS addresses (loop-invariant): write 4x b64, read 2x b128
    int pw[4], pr[2];
#pragma unroll
    for (int kf = 0; kf < 4; kf++)
        pw[kf] = qcol * 64 + (((kf * 2 + (quad >> 1)) ^ (qcol & 7)) * 8) + (quad & 1) * 4;
#pragma unroll
    for (int ks = 0; ks < 2; ks++)
        pr[ks] = qcol * 64 + (((ks * 4 + quad) ^ (qcol & 7)) * 8);

    float m_i = -1e30f, l_i = 0.f;
    v4f acc[8];
#pragma unroll
    for (int c = 0; c < 8; c++) acc[c] = (v4f){0.f, 0.f, 0.f, 0.f};

    for (int kb = 0; kb < SS; kb += 64) {
        __syncthreads();   // previous tile's LDS reads complete
#pragma unroll
        for (int j = 0; j < 4; j++)
            __builtin_amdgcn_global_load_lds((const GLOBAL_AS void*)(kcur + ko[j]),
                                             (LDS_AS void*)(kl0 + j * 4 * 128), 16, 0, 0);
#pragma unroll
        for (int j = 0; j < 4; j++)
            __builtin_amdgcn_global_load_lds((const GLOBAL_AS void*)(vcur + vo0 + j * 8 * SS),
                                             (LDS_AS void*)(vl0 + j * 8 * 64), 16, 0, 0);
        kcur += (size_t)64 * DD;
        vcur += 64;
        __syncthreads();   // staging drained

        // S^T = K.Q^T : 16 MFMA 16x16x32, fragments from swizzled sK
        v4f s[4];
#pragma unroll
        for (int kf = 0; kf < 4; kf++) {
            s[kf] = (v4f){0.f, 0.f, 0.f, 0.f};
#pragma unroll
            for (int kk = 0; kk < 4; kk++) {
                v8bf ak = __builtin_bit_cast(v8bf,
                    *(const v8s*)&sK[(kf * 16 + qcol) * 128 + (((kk * 4 + quad) ^ qcol) * 8)]);
                s[kf] = __builtin_amdgcn_mfma_f32_16x16x32_bf16(ak, bq[kk], s[kf], 0, 0, 0);
            }
        }

        // online softmax over 64 keys (base-2; log2(e) folded into qh scale)
        float mx = -1e30f;
#pragma unroll
        for (int kf = 0; kf < 4; kf++)
#pragma unroll
            for (int r = 0; r < 4; r++) mx = fmaxf(mx, s[kf][r]);
        mx = fmaxf(mx, __shfl_xor(mx, 16));
        mx = fmaxf(mx, __shfl_xor(mx, 32));
        float m_new = fmaxf(m_i, mx);
        float rs = 0.f;
        v4s p[4];
#pragma unroll
        for (int kf = 0; kf < 4; kf++)
#pragma unroll
            for (int r = 0; r < 4; r++) {
                float pf = exp2f(s[kf][r] - m_new);
                rs += pf;
                p[kf][r] = (short)f2b(pf);
            }
        rs += __shfl_xor(rs, 16);
        rs += __shfl_xor(rs, 32);
        if (__any(mx > m_i)) {          // skip O-rescale when no max grew
            float alpha = exp2f(m_i - m_new);
            l_i *= alpha;
#pragma unroll
            for (int c = 0; c < 8; c++) {
                acc[c][0] *= alpha; acc[c][1] *= alpha;
                acc[c][2] *= alpha; acc[c][3] *= alpha;
            }
        }
        l_i += rs;
        m_i = m_new;

        // P -> LDS (own wave slice), then PV: 16 MFMA 16x16x32
#pragma unroll
        for (int kf = 0; kf < 4; kf++)
            *(v4s*)&sPw[pw[kf]] = p[kf];

#pragma unroll
        for (int ks = 0; ks < 2; ks++) {
            v8bf pb = ldsv8(&sPw[pr[ks]]);
#pragma unroll
            for (int c = 0; c < 8; c++) {
                v8bf av = ldsv8(&sV[(c * 16 + qcol) * 64 + (((ks * 4 + quad) ^ (qcol & 7)) * 8)]);
                acc[c] = __builtin_amdgcn_mfma_f32_16x16x32_bf16(av, pb, acc[c], 0, 0, 0);
            }
        }
    }

    float rl = 1.0f / l_i;
    float* op = out + (size_t)(b * SS + q0 + qcol) * DD + h * DHD;
#pragma unroll
    for (int c = 0; c < 8; c++)
#pragma unroll
        for (int r = 0; r < 4; r++)
            op[c * 16 + quad * 4 + r] = acc[c][r] * rl;
}

// ---------------------------------------------------------------------------
// Launch. ws layout (needs 136 MB):
//   abuf @ 0 MB (32) | wbuf @ 32 (8) | qh @ 40 (32) | kh @ 72 (32) | vt @ 104 (32)
// ---------------------------------------------------------------------------
extern "C" void kernel_launch(void* const* d_in, const int* in_sizes, int n_in,
                              void* d_out, int out_size, void* d_ws, size_t ws_size,
                              hipStream_t stream) {
    const float* ins[3]  = {(const float*)d_in[0], (const float*)d_in[1], (const float*)d_in[2]};
    const float* wins[3] = {(const float*)d_in[3], (const float*)d_in[4], (const float*)d_in[5]};
    char* ws = (char*)d_ws;
    unsigned short* abuf = (unsigned short*)(ws);
    unsigned short* wbuf = (unsigned short*)(ws + (size_t)32 * 1024 * 1024);
    unsigned short* qhb  = (unsigned short*)(ws + (size_t)40 * 1024 * 1024);
    unsigned short* khb  = (unsigned short*)(ws + (size_t)72 * 1024 * 1024);
    unsigned short* vtb  = (unsigned short*)(ws + (size_t)104 * 1024 * 1024);
    float* out = (float*)d_out;

    unsigned short* outs[3] = {qhb, khb, vtb};
    const float qscale = 0.12753139626246937f;  // log2(e)/sqrt(128)
    float scales[3] = {qscale, 1.f, 1.f};
    int   vmodes[3] = {0, 0, 1};

    const int M = BB * SS, N = DD, K = DD;
    const int grid = (M / 256) * (N / 256);   // 32*8 = 256 WGs = 1/CU

    for (int i = 0; i < 3; i++) {
        cvt_f32_bf16<<<dim3(4096), dim3(256), 0, stream>>>(ins[i], abuf, (BB * SS * DD) / 4);
        wtrans_kernel<<<dim3(32, 32), dim3(256), 0, stream>>>(wins[i], wbuf);
        gemm256<<<dim3(grid), dim3(512), 0, stream>>>(abuf, wbuf, outs[i],
                                                      scales[i], vmodes[i], M, N, K);
    }
    attn_kernel<<<dim3(SS / 64, HH, BB), dim3(256), 0, stream>>>(qhb, khb, vtb, out);
}